// Round 1
// baseline (268.066 us; speedup 1.0000x reference)
//
#include <hip/hip_runtime.h>
#include <math.h>

// Problem constants
constexpr int kB = 2;
constexpr int kC = 128;
constexpr int kN = 784;
constexpr float kInvT = 1.0f / 11.313708498984761f;  // 1/sqrt(C)
constexpr float kInvC = 1.0f / 128.0f;

// ---------------- Kernel 1: attn = softmax_q( mean_c |q/T - k| ) ----------------
// One block handles (b, 7 consecutive k-rows). 256 threads; each thread owns
// q = {t, t+256, t+512, t+768} (last slot partially valid since 784 = 3*256+16).
constexpr int KT = 7;             // k-rows per block; 784/7 = 112 exactly
constexpr int QS = 4;             // q slots per thread

__device__ inline float wave_max(float v) {
#pragma unroll
    for (int o = 32; o > 0; o >>= 1) v = fmaxf(v, __shfl_xor(v, o, 64));
    return v;
}
__device__ inline float wave_sum(float v) {
#pragma unroll
    for (int o = 32; o > 0; o >>= 1) v += __shfl_xor(v, o, 64);
    return v;
}

__global__ __launch_bounds__(256) void attn_kernel(const float* __restrict__ qg,
                                                   const float* __restrict__ kg,
                                                   float* __restrict__ attn) {
    const int nblk_per_b = kN / KT;  // 112
    const int b = blockIdx.x / nblk_per_b;
    const int kt = blockIdx.x % nblk_per_b;
    const int k0 = kt * KT;
    const int t = threadIdx.x;

    __shared__ float kc[KT][kC];       // staged k columns (broadcast reads)
    __shared__ float xred[4][KT];      // cross-wave reduction scratch

    // Stage the 7 k-columns: k[b, c, k0+kk]
    const float* kb = kg + (size_t)b * kC * kN;
    for (int i = t; i < KT * kC; i += 256) {
        int kk = i / kC, c = i % kC;
        kc[kk][c] = kb[(size_t)c * kN + (k0 + kk)];
    }
    __syncthreads();

    float acc[QS][KT];
#pragma unroll
    for (int qi = 0; qi < QS; ++qi)
#pragma unroll
        for (int kk = 0; kk < KT; ++kk) acc[qi][kk] = 0.0f;

    const float* qb = qg + (size_t)b * kC * kN;
    for (int c = 0; c < kC; ++c) {
        float qv[QS];
#pragma unroll
        for (int qi = 0; qi < QS; ++qi) {
            int qq = qi * 256 + t;
            qv[qi] = (qq < kN) ? qb[(size_t)c * kN + qq] * kInvT : 0.0f;
        }
#pragma unroll
        for (int kk = 0; kk < KT; ++kk) {
            float kv = kc[kk][c];
#pragma unroll
            for (int qi = 0; qi < QS; ++qi)
                acc[qi][kk] += fabsf(qv[qi] - kv);  // sub + add-with-abs-modifier
        }
    }

    // ---- softmax over q per k-row (values are raw sums; mean = *kInvC) ----
    const int lane = t & 63, wid = t >> 6;

    float m[KT];
#pragma unroll
    for (int kk = 0; kk < KT; ++kk) {
        float v = -1e30f;
#pragma unroll
        for (int qi = 0; qi < QS; ++qi) {
            int qq = qi * 256 + t;
            if (qq < kN) v = fmaxf(v, acc[qi][kk]);
        }
        v = wave_max(v);
        if (lane == 0) xred[wid][kk] = v;
    }
    __syncthreads();
#pragma unroll
    for (int kk = 0; kk < KT; ++kk)
        m[kk] = fmaxf(fmaxf(xred[0][kk], xred[1][kk]),
                      fmaxf(xred[2][kk], xred[3][kk]));
    __syncthreads();  // protect xred before reuse

#pragma unroll
    for (int kk = 0; kk < KT; ++kk) {
        float lsum = 0.0f;
#pragma unroll
        for (int qi = 0; qi < QS; ++qi) {
            int qq = qi * 256 + t;
            float p = (qq < kN) ? __expf((acc[qi][kk] - m[kk]) * kInvC) : 0.0f;
            acc[qi][kk] = p;  // reuse registers
            lsum += p;
        }
        lsum = wave_sum(lsum);
        if (lane == 0) xred[wid][kk] = lsum;
    }
    __syncthreads();

#pragma unroll
    for (int kk = 0; kk < KT; ++kk) {
        float inv = 1.0f / (xred[0][kk] + xred[1][kk] + xred[2][kk] + xred[3][kk]);
        float* arow = attn + ((size_t)b * kN + (k0 + kk)) * kN;
#pragma unroll
        for (int qi = 0; qi < QS; ++qi) {
            int qq = qi * 256 + t;
            if (qq < kN) arow[qq] = acc[qi][kk] * inv;
        }
    }
}

// ---------------- Kernel 2: out[b,c,k] = sum_q v[b,c,q] * attn[b,k,q] ----------------
// fp32 VALU GEMM. Block tile: 128c x 32k, q reduction split 4 ways across blocks
// (atomicAdd into zeroed out). Per thread: 4c x 4k register tile, b128 LDS reads.
constexpr int KTILE = 32;
constexpr int NTK = (kN + KTILE - 1) / KTILE;  // 25
constexpr int QSPLIT = 4;
constexpr int QPB = kN / QSPLIT;               // 196
constexpr int QCH = 28;                        // q chunk; 196 = 7*28

__global__ __launch_bounds__(256) void bmm_kernel(const float* __restrict__ vg,
                                                  const float* __restrict__ attn,
                                                  float* __restrict__ out) {
    const int bid = blockIdx.x;
    const int qs = bid % QSPLIT;
    const int kt = (bid / QSPLIT) % NTK;
    const int b = bid / (QSPLIT * NTK);
    const int k0 = kt * KTILE;
    const int q_base = qs * QPB;
    const int t = threadIdx.x;

    __shared__ float vT[QCH][kC + 4];      // [qq][c], row = 132 floats = 528B (16B-mult)
    __shared__ float aT[QCH][KTILE + 4];   // [qq][k], row = 36 floats  = 144B (16B-mult)

    const int ct = t & 31;       // 0..31 -> c0 = ct*4
    const int ktr = t >> 5;      // 0..7  -> kk0 = ktr*4
    const int c0 = ct * 4;
    const int kk0 = ktr * 4;

    float acc[4][4];
#pragma unroll
    for (int i = 0; i < 4; ++i)
#pragma unroll
        for (int j = 0; j < 4; ++j) acc[i][j] = 0.0f;

    const float* vb = vg + (size_t)b * kC * kN;
    const float* ab = attn + (size_t)b * kN * kN;

    for (int qc = 0; qc < QPB; qc += QCH) {
        const int q0 = q_base + qc;
        // stage v chunk: 128 x 28 = 3584 floats (14 per thread), coalesced along q
        for (int i = t; i < kC * QCH; i += 256) {
            int c = i / QCH, qq = i % QCH;
            vT[qq][c] = vb[(size_t)c * kN + q0 + qq];
        }
        // stage attn chunk: 32 x 28 = 896 floats
        for (int i = t; i < KTILE * QCH; i += 256) {
            int kkk = i / QCH, qq = i % QCH;
            int krow = k0 + kkk;
            aT[qq][kkk] = (krow < kN) ? ab[(size_t)krow * kN + q0 + qq] : 0.0f;
        }
        __syncthreads();

#pragma unroll 4
        for (int qq = 0; qq < QCH; ++qq) {
            float4 vv = *reinterpret_cast<const float4*>(&vT[qq][c0]);
            float4 aa = *reinterpret_cast<const float4*>(&aT[qq][kk0]);
            float vvf[4] = {vv.x, vv.y, vv.z, vv.w};
            float aaf[4] = {aa.x, aa.y, aa.z, aa.w};
#pragma unroll
            for (int i = 0; i < 4; ++i)
#pragma unroll
                for (int j = 0; j < 4; ++j) acc[i][j] += vvf[i] * aaf[j];
        }
        __syncthreads();
    }

#pragma unroll
    for (int i = 0; i < 4; ++i) {
        int c = c0 + i;
#pragma unroll
        for (int j = 0; j < 4; ++j) {
            int krow = k0 + kk0 + j;
            if (krow < kN)
                atomicAdd(&out[(size_t)b * kC * kN + (size_t)c * kN + krow], acc[i][j]);
        }
    }
}

extern "C" void kernel_launch(void* const* d_in, const int* in_sizes, int n_in,
                              void* d_out, int out_size, void* d_ws, size_t ws_size,
                              hipStream_t stream) {
    const float* q = (const float*)d_in[0];
    const float* k = (const float*)d_in[1];
    const float* v = (const float*)d_in[2];

    float* out = (float*)d_out;                        // [B, C, N]
    float* attn = out + (size_t)kB * kC * kN;          // [B, N, N]

    // out region is accumulated via atomics -> zero it (memset node is graph-capturable)
    hipMemsetAsync(out, 0, (size_t)kB * kC * kN * sizeof(float), stream);

    attn_kernel<<<kB * (kN / KT), 256, 0, stream>>>(q, k, attn);
    bmm_kernel<<<kB * NTK * QSPLIT, 256, 0, stream>>>(v, attn, out);
}

// Round 2
// 128.869 us; speedup vs baseline: 2.0801x; 2.0801x over previous
//
#include <hip/hip_runtime.h>
#include <math.h>

// Problem constants
constexpr int kB = 2;
constexpr int kC = 128;
constexpr int kN = 784;
constexpr float kInvT = 1.0f / 11.313708498984761f;  // 1/sqrt(C)
constexpr float kInvC = 1.0f / 128.0f;

__device__ inline float wave_max(float v) {
#pragma unroll
    for (int o = 32; o > 0; o >>= 1) v = fmaxf(v, __shfl_xor(v, o, 64));
    return v;
}
__device__ inline float wave_sum(float v) {
#pragma unroll
    for (int o = 32; o > 0; o >>= 1) v += __shfl_xor(v, o, 64);
    return v;
}

// ---------------- Kernel 1: D[b,k,q] = sum_c |q[c,q]/T - k[c,k]|  (raw sums) ----------------
// GEMM-style tiling: block = (b, 32 k-rows, 64 q-cols). 650 blocks for parallelism.
// Thread: 2k x 4q register tile; per c-iter: 1 ds_read_b64 (k, broadcast) +
// 1 ds_read_b128 (q, 2-way = free) + 16 VALU. VALU-bound by design.
constexpr int TK = 32;
constexpr int TQ = 64;
constexpr int NKT = (kN + TK - 1) / TK;  // 25
constexpr int NQT = (kN + TQ - 1) / TQ;  // 13

__global__ __launch_bounds__(256) void dist_kernel(const float* __restrict__ qg,
                                                   const float* __restrict__ kg,
                                                   float* __restrict__ D) {
    const int qt = blockIdx.x % NQT;
    const int kt = (blockIdx.x / NQT) % NKT;
    const int b  = blockIdx.x / (NQT * NKT);
    const int k0 = kt * TK;
    const int q0 = qt * TQ;
    const int t  = threadIdx.x;

    __shared__ float ks[kC][TK];   // 16 KB
    __shared__ float qs[kC][TQ];   // 32 KB

    const float* kb = kg + (size_t)b * kC * kN;
    const float* qb = qg + (size_t)b * kC * kN;

    // Stage k-tile (coalesced along x; LDS writes linear -> conflict-free)
    for (int i = t; i < kC * TK; i += 256) {
        int c = i >> 5, x = i & 31;
        ks[c][x] = kb[(size_t)c * kN + min(k0 + x, kN - 1)];
    }
    // Stage q-tile, pre-scaled by 1/T
    for (int i = t; i < kC * TQ; i += 256) {
        int c = i >> 6, x = i & 63;
        qs[c][x] = qb[(size_t)c * kN + min(q0 + x, kN - 1)] * kInvT;
    }
    __syncthreads();

    const int qx = (t & 15) * 4;   // 16 q-groups
    const int kx = (t >> 4) * 2;   // 16 k-groups

    float acc[2][4];
#pragma unroll
    for (int i = 0; i < 2; ++i)
#pragma unroll
        for (int j = 0; j < 4; ++j) acc[i][j] = 0.0f;

#pragma unroll 2
    for (int c = 0; c < kC; ++c) {
        float2 kv = *reinterpret_cast<const float2*>(&ks[c][kx]);
        float4 qv = *reinterpret_cast<const float4*>(&qs[c][qx]);
        float kf[2] = {kv.x, kv.y};
        float qf[4] = {qv.x, qv.y, qv.z, qv.w};
#pragma unroll
        for (int i = 0; i < 2; ++i)
#pragma unroll
            for (int j = 0; j < 4; ++j) acc[i][j] += fabsf(qf[j] - kf[i]);
    }

    // Write raw sums (mean scaling folded into softmax). 784 % 4 == 0 so a
    // float4 store is either fully valid or fully invalid.
    if (q0 + qx < kN) {
#pragma unroll
        for (int i = 0; i < 2; ++i) {
            int krow = k0 + kx + i;
            if (krow < kN) {
                float4 o = make_float4(acc[i][0], acc[i][1], acc[i][2], acc[i][3]);
                *reinterpret_cast<float4*>(&D[((size_t)b * kN + krow) * kN + q0 + qx]) = o;
            }
        }
    }
}

// ---------------- Kernel 2: in-place row softmax over q (with mean scaling) ----------------
// One block per (b,k) row; 1568 blocks.
__global__ __launch_bounds__(256) void softmax_kernel(float* __restrict__ A) {
    float* row = A + (size_t)blockIdx.x * kN;
    const int t = threadIdx.x;
    const int lane = t & 63, wid = t >> 6;
    __shared__ float xred[4];

    float x[4];
#pragma unroll
    for (int s = 0; s < 4; ++s) {
        int qq = t + s * 256;
        x[s] = (qq < kN) ? row[qq] : -1e30f;
    }
    float m = fmaxf(fmaxf(x[0], x[1]), fmaxf(x[2], x[3]));
    m = wave_max(m);
    if (lane == 0) xred[wid] = m;
    __syncthreads();
    m = fmaxf(fmaxf(xred[0], xred[1]), fmaxf(xred[2], xred[3]));
    __syncthreads();

    float lsum = 0.0f;
#pragma unroll
    for (int s = 0; s < 4; ++s) {
        int qq = t + s * 256;
        float p = (qq < kN) ? __expf((x[s] - m) * kInvC) : 0.0f;
        x[s] = p;
        lsum += p;
    }
    lsum = wave_sum(lsum);
    if (lane == 0) xred[wid] = lsum;
    __syncthreads();
    float inv = 1.0f / (xred[0] + xred[1] + xred[2] + xred[3]);
#pragma unroll
    for (int s = 0; s < 4; ++s) {
        int qq = t + s * 256;
        if (qq < kN) row[qq] = x[s] * inv;
    }
}

// ---------------- Kernel 3: out[b,c,k] = sum_q v[b,c,q] * attn[b,k,q] ----------------
// 64c x 64k block tile, q split 8 ways (98 q each), atomicAdd into zeroed out.
constexpr int BCT = 64;
constexpr int BKT = 64;
constexpr int NCT = kC / BCT;                   // 2
constexpr int NKT2 = (kN + BKT - 1) / BKT;      // 13
constexpr int QSP = 8;
constexpr int QPB = kN / QSP;                   // 98
constexpr int QCH = 14;                         // 98 = 7*14

__global__ __launch_bounds__(256) void bmm_kernel(const float* __restrict__ vg,
                                                  const float* __restrict__ attn,
                                                  float* __restrict__ out) {
    const int bid = blockIdx.x;
    const int qs  = bid % QSP;
    const int kt  = (bid / QSP) % NKT2;
    const int ct  = (bid / (QSP * NKT2)) % NCT;
    const int b   = bid / (QSP * NKT2 * NCT);
    const int k0  = kt * BKT;
    const int c0  = ct * BCT;
    const int qb0 = qs * QPB;
    const int t   = threadIdx.x;

    __shared__ float vT[QCH][BCT + 4];   // stride 68 floats (16B-mult, b128-aligned)
    __shared__ float aT[QCH][BKT + 4];

    const int c0l = (t & 15) * 4;
    const int k0l = (t >> 4) * 4;

    float acc[4][4];
#pragma unroll
    for (int i = 0; i < 4; ++i)
#pragma unroll
        for (int j = 0; j < 4; ++j) acc[i][j] = 0.0f;

    const float* vb = vg + (size_t)b * kC * kN;
    const float* ab = attn + (size_t)b * kN * kN;

    for (int qc = 0; qc < QPB; qc += QCH) {
        const int q0 = qb0 + qc;
        // stage v chunk: 64c x 14q (coalesced 14-float segments along q)
        for (int i = t; i < BCT * QCH; i += 256) {
            int cc = i / QCH, qq = i % QCH;
            vT[qq][cc] = vb[(size_t)(c0 + cc) * kN + q0 + qq];
        }
        // stage attn chunk: 64k x 14q (clamp k; garbage cols never read by valid j)
        for (int i = t; i < BKT * QCH; i += 256) {
            int kk = i / QCH, qq = i % QCH;
            aT[qq][kk] = ab[(size_t)min(k0 + kk, kN - 1) * kN + q0 + qq];
        }
        __syncthreads();

#pragma unroll 2
        for (int qq = 0; qq < QCH; ++qq) {
            float4 vv = *reinterpret_cast<const float4*>(&vT[qq][c0l]);
            float4 aa = *reinterpret_cast<const float4*>(&aT[qq][k0l]);
            float vf[4] = {vv.x, vv.y, vv.z, vv.w};
            float af[4] = {aa.x, aa.y, aa.z, aa.w};
#pragma unroll
            for (int i = 0; i < 4; ++i)
#pragma unroll
                for (int j = 0; j < 4; ++j) acc[i][j] += vf[i] * af[j];
        }
        __syncthreads();
    }

#pragma unroll
    for (int i = 0; i < 4; ++i) {
        int c = c0 + c0l + i;
#pragma unroll
        for (int j = 0; j < 4; ++j) {
            int krow = k0 + k0l + j;
            if (krow < kN)
                atomicAdd(&out[((size_t)b * kC + c) * kN + krow], acc[i][j]);
        }
    }
}

extern "C" void kernel_launch(void* const* d_in, const int* in_sizes, int n_in,
                              void* d_out, int out_size, void* d_ws, size_t ws_size,
                              hipStream_t stream) {
    const float* q = (const float*)d_in[0];
    const float* k = (const float*)d_in[1];
    const float* v = (const float*)d_in[2];

    float* out  = (float*)d_out;                  // [B, C, N]
    float* attn = out + (size_t)kB * kC * kN;     // [B, N, N] — also holds raw D pre-softmax

    hipMemsetAsync(out, 0, (size_t)kB * kC * kN * sizeof(float), stream);

    dist_kernel<<<kB * NKT * NQT, 256, 0, stream>>>(q, k, attn);
    softmax_kernel<<<kB * kN, 256, 0, stream>>>(attn);
    bmm_kernel<<<kB * NCT * NKT2 * QSP, 256, 0, stream>>>(v, attn, out);
}

// Round 3
// 112.123 us; speedup vs baseline: 2.3908x; 1.1493x over previous
//
#include <hip/hip_runtime.h>
#include <math.h>

// Problem constants
constexpr int kB = 2;
constexpr int kC = 128;
constexpr int kN = 784;
constexpr float kInvT = 1.0f / 11.313708498984761f;  // 1/sqrt(C)
constexpr float kInvC = 1.0f / 128.0f;

__device__ inline float wave_max(float v) {
#pragma unroll
    for (int o = 32; o > 0; o >>= 1) v = fmaxf(v, __shfl_xor(v, o, 64));
    return v;
}
__device__ inline float wave_sum(float v) {
#pragma unroll
    for (int o = 32; o > 0; o >>= 1) v += __shfl_xor(v, o, 64);
    return v;
}

// ================= Kernel 1: D[b,k,q] = sum_c |q[c,q]/T - k[c,k]| =================
// 64k x 64q tile, 4k x 4q per thread, c split in 2 halves across blocks.
// Grid = 2b * 2c * 13 * 13 = 676. LDS 34.8 KB. Per c-iter: 2 ds_read_b128
// (2-way conflicts = free) + 32 VALU cyc -> ~1.5x LDS-bound ceiling.
constexpr int DT = 64;
constexpr int DNT = (kN + DT - 1) / DT;  // 13
constexpr int CSP = 2;
constexpr int CH = kC / CSP;             // 64
constexpr int DSTR = 68;                 // LDS row stride (68%32=4 -> 2-way max)

template <bool USE_WS>
__global__ __launch_bounds__(256) void dist_kernel(const float* __restrict__ qg,
                                                   const float* __restrict__ kg,
                                                   float* __restrict__ D0,
                                                   float* __restrict__ D1) {
    int bid = blockIdx.x;
    const int qt = bid % DNT; bid /= DNT;
    const int kt = bid % DNT; bid /= DNT;
    const int ch = bid & 1;   bid >>= 1;
    const int b  = bid;
    const int k0 = kt * DT;
    const int q0 = qt * DT;
    const int t  = threadIdx.x;

    __shared__ float ks[CH][DSTR];
    __shared__ float qs[CH][DSTR];

    const float* kb = kg + ((size_t)b * kC + ch * CH) * kN;
    const float* qb = qg + ((size_t)b * kC + ch * CH) * kN;

    // Stage both tiles: 4 iters x (2 float4 global loads + 2 float4 LDS writes).
    // Lane pattern: c = i>>4 (4 rows/wave), x4 = (i&15)*4 -> 256B global segments,
    // LDS write bank-starts spread 8 ways x4 banks -> 2-way = free.
#pragma unroll
    for (int i = t; i < CH * 16; i += 256) {
        const int c  = i >> 4;
        const int x4 = (i & 15) << 2;
        float4 kv = *reinterpret_cast<const float4*>(kb + (size_t)c * kN + min(k0 + x4, kN - 4));
        float4 qv = *reinterpret_cast<const float4*>(qb + (size_t)c * kN + min(q0 + x4, kN - 4));
        *reinterpret_cast<float4*>(&ks[c][x4]) = kv;
        qv.x *= kInvT; qv.y *= kInvT; qv.z *= kInvT; qv.w *= kInvT;
        *reinterpret_cast<float4*>(&qs[c][x4]) = qv;
    }
    __syncthreads();

    const int qx = (t & 15) << 2;   // 16 q-groups
    const int kx = (t >> 4) << 2;   // 16 k-groups

    float acc[4][4];
#pragma unroll
    for (int i = 0; i < 4; ++i)
#pragma unroll
        for (int j = 0; j < 4; ++j) acc[i][j] = 0.0f;

#pragma unroll 4
    for (int c = 0; c < CH; ++c) {
        float4 kv4 = *reinterpret_cast<const float4*>(&ks[c][kx]);
        float4 qv4 = *reinterpret_cast<const float4*>(&qs[c][qx]);
        float kf[4] = {kv4.x, kv4.y, kv4.z, kv4.w};
        float qf[4] = {qv4.x, qv4.y, qv4.z, qv4.w};
#pragma unroll
        for (int i = 0; i < 4; ++i)
#pragma unroll
            for (int j = 0; j < 4; ++j) acc[i][j] += fabsf(qf[j] - kf[i]);
    }

    const int qcol = q0 + qx;
    if (qcol < kN) {
        float* dst = (USE_WS && ch) ? D1 : D0;
#pragma unroll
        for (int i = 0; i < 4; ++i) {
            const int krow = k0 + kx + i;
            if (krow < kN) {
                const size_t off = ((size_t)b * kN + krow) * kN + qcol;
                if (USE_WS) {
                    *reinterpret_cast<float4*>(dst + off) =
                        make_float4(acc[i][0], acc[i][1], acc[i][2], acc[i][3]);
                } else {
                    atomicAdd(&D0[off + 0], acc[i][0]);
                    atomicAdd(&D0[off + 1], acc[i][1]);
                    atomicAdd(&D0[off + 2], acc[i][2]);
                    atomicAdd(&D0[off + 3], acc[i][3]);
                }
            }
        }
    }
}

// ================= Kernel 2: row softmax over q (fuses the two c-halves) =================
// One block per (b,k) row; 1568 blocks; float4 per thread (196 active).
template <bool SUM2>
__global__ __launch_bounds__(256) void softmax_kernel(float* __restrict__ A,
                                                      const float* __restrict__ W) {
    const size_t row = (size_t)blockIdx.x * kN;
    float4* A4 = reinterpret_cast<float4*>(A + row);
    const float4* W4 = reinterpret_cast<const float4*>(W + row);
    const int t = threadIdx.x;
    const int lane = t & 63, wid = t >> 6;
    const bool act = t < (kN / 4);  // 196
    __shared__ float xred[4];

    float4 x = make_float4(-1e30f, -1e30f, -1e30f, -1e30f);
    if (act) {
        x = A4[t];
        if (SUM2) {
            float4 w = W4[t];
            x.x += w.x; x.y += w.y; x.z += w.z; x.w += w.w;
        }
    }

    float m = fmaxf(fmaxf(x.x, x.y), fmaxf(x.z, x.w));
    m = wave_max(m);
    if (lane == 0) xred[wid] = m;
    __syncthreads();
    m = fmaxf(fmaxf(xred[0], xred[1]), fmaxf(xred[2], xred[3]));
    __syncthreads();

    float4 p;
    p.x = __expf((x.x - m) * kInvC);
    p.y = __expf((x.y - m) * kInvC);
    p.z = __expf((x.z - m) * kInvC);
    p.w = __expf((x.w - m) * kInvC);
    float lsum = p.x + p.y + p.z + p.w;  // inactive lanes: exp(-huge)=0
    lsum = wave_sum(lsum);
    if (lane == 0) xred[wid] = lsum;
    __syncthreads();
    const float inv = 1.0f / (xred[0] + xred[1] + xred[2] + xred[3]);
    if (act) {
        p.x *= inv; p.y *= inv; p.z *= inv; p.w *= inv;
        A4[t] = p;
    }
}

// ================= Kernel 3: out[b,c,k] = sum_q v[b,c,q] * attn[b,k,q] =================
// 64c x 64k tile, 4c x 4k per thread, qsplit 7 (112 = 7 chunks x 16 q exact).
// Grid = 2b * 2c * 13k * 7q = 364. Conflict-free transposed staging:
// float4 global read + 4 scalar LDS writes (2-way bank pattern = free).
constexpr int BKT = 64;
constexpr int NKT2 = (kN + BKT - 1) / BKT;  // 13
constexpr int QSP = 7;
constexpr int QPB = kN / QSP;               // 112
constexpr int QCH = 16;
constexpr int BSTR = 68;

__global__ __launch_bounds__(256) void bmm_kernel(const float* __restrict__ vg,
                                                  const float* __restrict__ attn,
                                                  float* __restrict__ out) {
    int bid = blockIdx.x;
    const int qs = bid % QSP;            bid /= QSP;
    const int kt = bid % NKT2;           bid /= NKT2;
    const int ct = bid & 1;              bid >>= 1;
    const int b  = bid;
    const int k0 = kt * BKT;
    const int c0 = ct * 64;
    const int qb0 = qs * QPB;
    const int t = threadIdx.x;

    __shared__ float vT[QCH][BSTR];
    __shared__ float aT[QCH][BSTR];

    const int cc = t >> 2;               // 0..63 (staging row)
    const int q4 = (t & 3) << 2;         // 0,4,8,12 (staging q group)
    const int c0l = (t & 15) << 2;       // compute tile c
    const int k0l = (t >> 4) << 2;       // compute tile k

    float acc[4][4];
#pragma unroll
    for (int i = 0; i < 4; ++i)
#pragma unroll
        for (int j = 0; j < 4; ++j) acc[i][j] = 0.0f;

    const float* vb = vg + ((size_t)b * kC + c0) * kN;
    const float* ab = attn + (size_t)b * kN * kN;
    const int krow_st = min(k0 + cc, kN - 1);  // clamp: pad rows never stored

    for (int qc = 0; qc < QPB; qc += QCH) {
        const int q0 = qb0 + qc;
        // prefetch before the barrier so the global load overlaps prior compute
        float4 vv = *reinterpret_cast<const float4*>(vb + (size_t)cc * kN + q0 + q4);
        float4 av = *reinterpret_cast<const float4*>(ab + (size_t)krow_st * kN + q0 + q4);
        __syncthreads();  // previous chunk's reads complete
        vT[q4 + 0][cc] = vv.x; vT[q4 + 1][cc] = vv.y;
        vT[q4 + 2][cc] = vv.z; vT[q4 + 3][cc] = vv.w;
        aT[q4 + 0][cc] = av.x; aT[q4 + 1][cc] = av.y;
        aT[q4 + 2][cc] = av.z; aT[q4 + 3][cc] = av.w;
        __syncthreads();

#pragma unroll
        for (int qq = 0; qq < QCH; ++qq) {
            float4 vf4 = *reinterpret_cast<const float4*>(&vT[qq][c0l]);
            float4 af4 = *reinterpret_cast<const float4*>(&aT[qq][k0l]);
            float vf[4] = {vf4.x, vf4.y, vf4.z, vf4.w};
            float af[4] = {af4.x, af4.y, af4.z, af4.w};
#pragma unroll
            for (int i = 0; i < 4; ++i)
#pragma unroll
                for (int j = 0; j < 4; ++j) acc[i][j] += vf[i] * af[j];
        }
    }

#pragma unroll
    for (int i = 0; i < 4; ++i) {
        const int c = c0 + c0l + i;
#pragma unroll
        for (int j = 0; j < 4; ++j) {
            const int krow = k0 + k0l + j;
            if (krow < kN)
                atomicAdd(&out[((size_t)b * kC + c) * kN + krow], acc[i][j]);
        }
    }
}

extern "C" void kernel_launch(void* const* d_in, const int* in_sizes, int n_in,
                              void* d_out, int out_size, void* d_ws, size_t ws_size,
                              hipStream_t stream) {
    const float* q = (const float*)d_in[0];
    const float* k = (const float*)d_in[1];
    const float* v = (const float*)d_in[2];

    float* out  = (float*)d_out;                  // [B, C, N]
    float* attn = out + (size_t)kB * kC * kN;     // [B, N, N]
    float* wsD  = (float*)d_ws;                   // second c-half of D

    const size_t attn_bytes = (size_t)kB * kN * kN * sizeof(float);
    const bool use_ws = ws_size >= attn_bytes;

    hipMemsetAsync(out, 0, (size_t)kB * kC * kN * sizeof(float), stream);

    if (use_ws) {
        dist_kernel<true><<<kB * CSP * DNT * DNT, 256, 0, stream>>>(q, k, attn, wsD);
        softmax_kernel<true><<<kB * kN, 256, 0, stream>>>(attn, wsD);
    } else {
        hipMemsetAsync(attn, 0, attn_bytes, stream);
        dist_kernel<false><<<kB * CSP * DNT * DNT, 256, 0, stream>>>(q, k, attn, nullptr);
        softmax_kernel<false><<<kB * kN, 256, 0, stream>>>(attn, attn);
    }
    bmm_kernel<<<kB * 2 * NKT2 * QSP, 256, 0, stream>>>(v, attn, out);
}